// Round 4
// baseline (175.316 us; speedup 1.0000x reference)
//
#include <hip/hip_runtime.h>

#define N_Q   16384
#define C_DIM 128
#define S_CAM 6
#define M_VAL 1400   // 28*50
#define D_Z   8
#define HF    28
#define WF    50
#define QPB   8      // gather: queries per block; 32 lanes/query
#define VP_BLOCKS 1050   // (S_CAM*M_VAL)/8
#define QP_BLOCKS 1024   // N_Q/16

typedef float f32x2 __attribute__((ext_vector_type(2)));

__device__ __forceinline__ bool mask_any(const unsigned char* __restrict__ mask,
                                         int mflag, size_t mbase){
  if(mflag==0){
    int any=0;
    #pragma unroll
    for(int d=0;d<D_Z;d++) any |= mask[mbase+d];
    return any!=0;
  } else if(mflag==1){
    const int* mp = (const int*)mask;  int any=0;
    #pragma unroll
    for(int d=0;d<D_Z;d++) any |= mp[mbase+d];
    return any!=0;
  } else {
    const long long* mp = (const long long*)mask;  long long any=0;
    #pragma unroll
    for(int d=0;d<D_Z;d++) any |= mp[mbase+d];
    return any!=0;
  }
}

// fp8x16 corner accumulate as f32x2 pairs -> v_pk_fma_f32.
__device__ __forceinline__ void corner_acc(const uint4 cv, const float wgt,
                                           f32x2* __restrict__ acc2){
  const f32x2 w2 = {wgt, wgt};
  const unsigned dw[4] = {cv.x, cv.y, cv.z, cv.w};
  #pragma unroll
  for(int j=0;j<4;j++){
    acc2[j*2+0] += w2 * __builtin_amdgcn_cvt_pk_f32_fp8(dw[j], false);
    acc2[j*2+1] += w2 * __builtin_amdgcn_cvt_pk_f32_fp8(dw[j], true);
  }
}

__device__ __forceinline__ void fma4(float4& a, const float4 t,
                                     const float4 w0, const float4 w1,
                                     const float4 w2, const float4 w3){
  a.x += t.x*w0.x + t.y*w1.x + t.z*w2.x + t.w*w3.x;
  a.y += t.x*w0.y + t.y*w1.y + t.z*w2.y + t.w*w3.y;
  a.z += t.x*w0.z + t.y*w1.z + t.z*w2.z + t.w*w3.z;
  a.w += t.x*w0.w + t.y*w1.w + t.z*w2.w + t.w*w3.w;
}

__device__ __forceinline__ void shfl4_add32(float4& a){
  a.x += __shfl_xor(a.x, 32);
  a.y += __shfl_xor(a.y, 32);
  a.z += __shfl_xor(a.z, 32);
  a.w += __shfl_xor(a.w, 32);
}

// ---------------------------------------------------------------------------
// K1 = value-proj (blocks 0..1049) UNION q-proj (blocks 1050..2073).
// R3/R4 theory: the GEMVs were re-loading 113KB of weights from L2 in every
// gather block (TA-pipe cost ~28us of the 75us wall); split them out with
// 4-queries-per-wave k-split amortization.
// WS-SAFETY (R4): offs/attns are staged in OUT rows (cols 0..95), not in the
// workspace -- out is dead until gather overwrites it, and workspace use
// stays at the proven ~1.08MB (flag + v8 only).
// ---------------------------------------------------------------------------
__global__ __launch_bounds__(256)
void prep_kernel(const float* __restrict__ value,
                 const float* __restrict__ Wv,
                 const float* __restrict__ bv,
                 unsigned char* __restrict__ v8,
                 const unsigned char* __restrict__ mask,
                 int* __restrict__ flag,
                 const float* __restrict__ query,
                 const float* __restrict__ query_pos,
                 const float* __restrict__ Wo, const float* __restrict__ bo,
                 const float* __restrict__ Wa, const float* __restrict__ ba,
                 float* __restrict__ out){
  __shared__ float smem[2048];               // vproj: tile+part; qproj: qtile[16][128]
  __shared__ float lbuf[16][32];             // qproj: raw logits for softmax
  __shared__ int s_cntA, s_cntB;
  const int tid = threadIdx.x;
  const int bid = blockIdx.x;

  if(bid < VP_BLOCKS){
    // ---------------- value projection -> fp8 ----------------
    float* tile = smem;                      // [8][128]
    float* part = smem + 1024;               // [8][128]
    const int c   = tid & 127;
    const int kh  = tid >> 7;
    const int r0  = bid * 8;
    if(bid==0 && tid==0){ s_cntA=0; s_cntB=0; }
    {
      const float4* src = (const float4*)(value + (size_t)r0*C_DIM);
      ((float4*)tile)[tid] = src[tid];
    }
    __syncthreads();
    float acc[8];
    {
      const float bias = kh ? 0.f : bv[c];
      #pragma unroll
      for(int r=0;r<8;r++) acc[r]=bias;
    }
    {
      const float* Wp = Wv + (size_t)kh*64*C_DIM + c;
      const int k00 = kh*64;
      for(int k0=0;k0<64;k0+=4){
        const float w0 = Wp[0];
        const float w1 = Wp[C_DIM];
        const float w2 = Wp[2*C_DIM];
        const float w3 = Wp[3*C_DIM];
        #pragma unroll
        for(int r=0;r<8;r++){
          const float4 t = *(const float4*)&tile[r*C_DIM + k00+k0];
          acc[r] += t.x*w0 + t.y*w1 + t.z*w2 + t.w*w3;
        }
        Wp += 4*C_DIM;
      }
    }
    if(kh){
      #pragma unroll
      for(int r=0;r<8;r++) part[r*C_DIM + c] = acc[r];
    }
    __syncthreads();
    if(!kh){
      #pragma unroll
      for(int r=0;r<8;r++){
        const float v = acc[r] + part[r*C_DIM + c];
        const int pk = __builtin_amdgcn_cvt_pk_fp8_f32(v, v, 0, false);
        v8[(size_t)(r0+r)*C_DIM + c] = (unsigned char)(pk & 0xff);
      }
    }
    if(bid==0){
      int a=0, b=0;
      for(int i=tid;i<1024;i+=256){
        const unsigned char v = mask[i];
        if(((i&3)!=0) && v) a=1;
        if(((i&7)==4) && v) b=1;
      }
      if(a) atomicOr(&s_cntA,1);
      if(b) atomicOr(&s_cntB,1);
      __syncthreads();
      if(tid==0) flag[0] = s_cntA ? 0 : (s_cntB ? 1 : 2);
    }
  } else {
    // ---------------- query projections + softmax ----------------
    const int qb = bid - VP_BLOCKS;
    const int n0 = qb * 16;
    float* qtile = smem;                     // [16][128]
    {
      const float4* qa = (const float4*)(query     + (size_t)n0*C_DIM);
      const float4* qp = (const float4*)(query_pos + (size_t)n0*C_DIM);
      #pragma unroll
      for(int j=0;j<2;j++){
        const int idx = tid + 256*j;
        const float4 A = qa[idx], B = qp[idx];
        *(float4*)&qtile[idx*4] = make_float4(A.x+B.x, A.y+B.y, A.z+B.z, A.w+B.w);
      }
    }
    __syncthreads();
    const int wi = tid >> 6;                 // wave: queries wi*4..wi*4+3
    const int ln = tid & 63;
    const int kh = ln >> 5;                  // k-half
    const int cg = ln & 31;                  // col-group
    float4 a0={0,0,0,0}, a1={0,0,0,0}, a2={0,0,0,0}, a3={0,0,0,0};
    if(cg < 24){
      const float* Wp; int stride; const float* bptr;
      if(cg < 16){ Wp = Wo + cg*4;      stride = 64; bptr = &bo[cg*4]; }
      else       { Wp = Wa + (cg-16)*4; stride = 32; bptr = &ba[(cg-16)*4]; }
      if(kh==0){
        const float4 bb = *(const float4*)bptr;
        a0=bb; a1=bb; a2=bb; a3=bb;
      }
      Wp += (size_t)kh*64*stride;
      const float* q0 = &qtile[(wi*4+0)*C_DIM + kh*64];
      const float* q1 = &qtile[(wi*4+1)*C_DIM + kh*64];
      const float* q2 = &qtile[(wi*4+2)*C_DIM + kh*64];
      const float* q3 = &qtile[(wi*4+3)*C_DIM + kh*64];
      #pragma unroll 4
      for(int k0=0;k0<64;k0+=4){
        const float4 w0 = *(const float4*)&Wp[0];
        const float4 w1 = *(const float4*)&Wp[stride];
        const float4 w2 = *(const float4*)&Wp[2*stride];
        const float4 w3 = *(const float4*)&Wp[3*stride];
        fma4(a0, *(const float4*)&q0[k0], w0,w1,w2,w3);
        fma4(a1, *(const float4*)&q1[k0], w0,w1,w2,w3);
        fma4(a2, *(const float4*)&q2[k0], w0,w1,w2,w3);
        fma4(a3, *(const float4*)&q3[k0], w0,w1,w2,w3);
        Wp += 4*stride;
      }
    }
    shfl4_add32(a0); shfl4_add32(a1); shfl4_add32(a2); shfl4_add32(a3);
    if(cg < 16){
      const int c0 = cg*4;
      const int r  = wi*4 + kh*2;            // kh=0 -> rows 0,1; kh=1 -> rows 2,3
      const float4 sA = kh ? a2 : a0;
      const float4 sB = kh ? a3 : a1;
      *(float4*)&out[(size_t)(n0+r  )*C_DIM + c0] = sA;
      *(float4*)&out[(size_t)(n0+r+1)*C_DIM + c0] = sB;
    } else if(cg < 24){
      const int c0 = (cg-16)*4;
      const int r  = wi*4 + kh*2;
      *(float4*)&lbuf[r  ][c0] = kh ? a2 : a0;
      *(float4*)&lbuf[r+1][c0] = kh ? a3 : a1;
    }
    __syncthreads();
    if(tid < 64){                            // softmax over P=8: (q, h)
      const int q = tid >> 2, h = tid & 3;
      const float* L = &lbuf[q][h*8];
      float mx = L[0];
      #pragma unroll
      for(int p=1;p<8;p++) mx = fmaxf(mx, L[p]);
      float e[8], ssum = 0.f;
      #pragma unroll
      for(int p=0;p<8;p++){ e[p] = __expf(L[p]-mx); ssum += e[p]; }
      const float inv = 1.f/ssum;
      float* dst = &out[(size_t)(n0+q)*C_DIM + 64 + h*8];
      *(float4*)dst     = make_float4(e[0]*inv, e[1]*inv, e[2]*inv, e[3]*inv);
      *(float4*)(dst+4) = make_float4(e[4]*inv, e[5]*inv, e[6]*inv, e[7]*inv);
    }
  }
}

// ---------------------------------------------------------------------------
// K2: gather only. Stages this block's offs/attns rows from OUT (cols 0..95)
// into LDS, then overwrites the same rows with slots (block-local
// read-before-write; rows disjoint across blocks). fp8 gather unchanged:
// 32 lanes/query (pt-half x cam-half x 8x16ch), shuffle corner-merge.
// Per-wave VMEM ~58 (was 184) -> the scattered phase gets the full latency
// budget.
// ---------------------------------------------------------------------------
__global__ __launch_bounds__(256)
void gather_kernel(const unsigned char* __restrict__ v8,
                   const float* __restrict__ ref,
                   const unsigned char* __restrict__ mask,
                   const int* __restrict__ flag,
                   float* __restrict__ out){
  __shared__ float  offs[QPB][68];           // 68 mod 32 = 4
  __shared__ float  attns[QPB][36];
  __shared__ float2 refs[QPB][S_CAM*D_Z+1];  // 49 f2 rows
  __shared__ int    activ[QPB][S_CAM];
  __shared__ float  cinv[QPB];

  const int tid = threadIdx.x;
  const int n0  = blockIdx.x * QPB;
  const int mflag = flag[0];
  const int qi = tid >> 5;                   // query in block
  const int l  = tid & 31;                   // lane within query group

  // ---- staging: offs/attns from out rows, refs, activ, cinv ----
  if(tid < 192){                             // 8q x 24 f4 = offs(16) + attns(8)
    const int q = tid/24, j = tid%24;
    const float4 v = *(const float4*)&out[(size_t)(n0+q)*C_DIM + j*4];
    if(j<16) *(float4*)&offs[q][j*4] = v;
    else     *(float4*)&attns[q][(j-16)*4] = v;
  }
  {
    const int q = tid/48, r = tid%48;        // r = s*8+p
    refs[q][r] = ((const float2*)ref)[((size_t)(r>>3)*N_Q + (n0+q))*D_Z + (r&7)];
    if(tid < 128){
      const int e1 = tid + 256;
      const int q1 = e1/48, r1 = e1%48;
      refs[q1][r1] = ((const float2*)ref)[((size_t)(r1>>3)*N_Q + (n0+q1))*D_Z + (r1&7)];
    }
  }
  if(tid < QPB*S_CAM){
    const int q2 = tid / S_CAM, s = tid % S_CAM;
    activ[q2][s] = mask_any(mask, mflag, ((size_t)s*N_Q + (n0+q2))*D_Z) ? 1 : 0;
  } else if(tid < QPB*S_CAM + QPB){
    const int q2 = tid - QPB*S_CAM;
    int c = 0;
    #pragma unroll
    for(int s=0;s<S_CAM;s++)
      c += mask_any(mask, mflag, ((size_t)s*N_Q + (n0+q2))*D_Z) ? 1 : 0;
    cinv[q2] = 1.f / fmaxf((float)c, 1.f);
  }
  __syncthreads();                           // oa fully staged before overwrite

  // ---- gather: 3 cams x 4 points per lane ----
  const int pg  = l >> 4;                    // points pg*4 .. pg*4+3
  const int sg  = (l >> 3) & 1;              // cams sg*3 .. sg*3+2
  const int ll  = l & 7;                     // 16-ch group
  const int gch = ll*16;
  const int gh  = ll >> 1;                   // head (32 ch/head)
  f32x2 acc2[8];
  #pragma unroll
  for(int i=0;i<8;i++) acc2[i] = (f32x2){0.f, 0.f};

  for(int s=sg*3; s<sg*3+3; s++){
    if(!activ[qi][s]) continue;
    const unsigned char* vb = v8 + (size_t)s*M_VAL*C_DIM + gch;
    #pragma unroll 2
    for(int pp=0;pp<4;pp++){                 // point p <-> z-anchor d=p (P//D==1)
      const int p = pg*4 + pp;
      const float2 r2 = refs[qi][s*8+p];
      const float ox = offs[qi][gh*16+p*2+0];
      const float oy = offs[qi][gh*16+p*2+1];
      const float x = fmaf(r2.x, (float)WF, ox - 0.5f);
      const float y = fmaf(r2.y, (float)HF, oy - 0.5f);
      const float x0f = floorf(x), y0f = floorf(y);
      const float fx = x - x0f,    fy = y - y0f;
      const int x0 = (int)x0f, y0 = (int)y0f;
      const int x1 = x0+1,     y1 = y0+1;
      const float at = attns[qi][gh*8+p];
      const float wx0 = (x0>=0 && x0<WF) ? (1.f-fx) : 0.f;
      const float wx1 = (x1>=0 && x1<WF) ? fx       : 0.f;
      const float wy0 = ((y0>=0 && y0<HF) ? (1.f-fy) : 0.f) * at;
      const float wy1 = ((y1>=0 && y1<HF) ? fy       : 0.f) * at;
      const int x0c = min(max(x0,0), WF-1), x1c = min(max(x1,0), WF-1);
      const int y0c = min(max(y0,0), HF-1), y1c = min(max(y1,0), HF-1);
      const float w00 = wx0*wy0, w01 = wx1*wy0, w10 = wx0*wy1, w11 = wx1*wy1;
      const uint4 c00 = *(const uint4*)(vb + (size_t)(y0c*WF+x0c)*C_DIM);
      const uint4 c01 = *(const uint4*)(vb + (size_t)(y0c*WF+x1c)*C_DIM);
      const uint4 c10 = *(const uint4*)(vb + (size_t)(y1c*WF+x0c)*C_DIM);
      const uint4 c11 = *(const uint4*)(vb + (size_t)(y1c*WF+x1c)*C_DIM);
      corner_acc(c00, w00, acc2);
      corner_acc(c01, w01, acc2);
      corner_acc(c10, w10, acc2);
      corner_acc(c11, w11, acc2);
    }
  }

  // ---- merge 4 (pg,sg) partials and store slots (overwrite own rows) ----
  float* accf = (float*)acc2;
  #pragma unroll
  for(int i=0;i<16;i++) accf[i] += __shfl_xor(accf[i], 16);  // merge pt halves
  #pragma unroll
  for(int i=0;i<16;i++) accf[i] += __shfl_xor(accf[i], 8);   // merge cam halves
  if(l < 8){
    const float inv = cinv[qi];
    float* dst = &out[(size_t)(n0+qi)*C_DIM + gch];
    #pragma unroll
    for(int i=0;i<4;i++)
      *(float4*)&dst[i*4] = make_float4(accf[i*4+0]*inv, accf[i*4+1]*inv,
                                        accf[i*4+2]*inv, accf[i*4+3]*inv);
  }
}

// ---------------------------------------------------------------------------
// K3: out-proj + bias + residual, IN-PLACE on out. 4 queries/wave k-split:
// the wave stages its own 4 slot-rows into LDS (wave-internal order: DS ops
// complete in order, no barrier), GEMVs against Wout (16 weight-loads/query),
// merges k-halves by shuffle, adds bias+residual, overwrites the same rows.
// ---------------------------------------------------------------------------
__global__ __launch_bounds__(256)
void outproj_kernel(const float* __restrict__ Wout,
                    const float* __restrict__ bout,
                    const float* __restrict__ query,
                    float* __restrict__ out){
  __shared__ float stile[4][4][C_DIM];       // [wave][qlocal][k]
  const int tid = threadIdx.x;
  const int n0  = blockIdx.x * 16;
  const int wi  = tid >> 6;
  const int ln  = tid & 63;
  const int kh  = ln >> 5;
  const int cg  = ln & 31;

  {
    const float4* src = (const float4*)(out + (size_t)(n0 + wi*4)*C_DIM);
    #pragma unroll
    for(int j=0;j<2;j++){
      const int idx = ln + 64*j;             // 0..127 over 4 rows x 32 f4
      const int r = idx >> 5, c4 = idx & 31;
      *(float4*)&stile[wi][r][c4*4] = src[idx];
    }
  }
  // wave-internal LDS write->read; compiler inserts the lgkm wait.
  float4 a0={0,0,0,0}, a1={0,0,0,0}, a2={0,0,0,0}, a3={0,0,0,0};
  {
    const float* Wp = Wout + (size_t)kh*64*C_DIM + cg*4;
    const float* s0 = &stile[wi][0][kh*64];
    const float* s1 = &stile[wi][1][kh*64];
    const float* s2 = &stile[wi][2][kh*64];
    const float* s3 = &stile[wi][3][kh*64];
    #pragma unroll 4
    for(int k0=0;k0<64;k0+=4){
      const float4 w0 = *(const float4*)&Wp[0];
      const float4 w1 = *(const float4*)&Wp[C_DIM];
      const float4 w2 = *(const float4*)&Wp[2*C_DIM];
      const float4 w3 = *(const float4*)&Wp[3*C_DIM];
      fma4(a0, *(const float4*)&s0[k0], w0,w1,w2,w3);
      fma4(a1, *(const float4*)&s1[k0], w0,w1,w2,w3);
      fma4(a2, *(const float4*)&s2[k0], w0,w1,w2,w3);
      fma4(a3, *(const float4*)&s3[k0], w0,w1,w2,w3);
      Wp += 4*C_DIM;
    }
  }
  shfl4_add32(a0); shfl4_add32(a1); shfl4_add32(a2); shfl4_add32(a3);
  {
    const int c0 = cg*4;
    const float4 bb = *(const float4*)&bout[c0];
    const int r = wi*4 + kh*2;               // kh=0 -> rows 0,1; kh=1 -> 2,3
    const float4 sA = kh ? a2 : a0;
    const float4 sB = kh ? a3 : a1;
    {
      const int n = n0 + r;
      const float4 rq = *(const float4*)&query[(size_t)n*C_DIM + c0];
      *(float4*)&out[(size_t)n*C_DIM + c0] =
        make_float4(sA.x+bb.x+rq.x, sA.y+bb.y+rq.y, sA.z+bb.z+rq.z, sA.w+bb.w+rq.w);
    }
    {
      const int n = n0 + r + 1;
      const float4 rq = *(const float4*)&query[(size_t)n*C_DIM + c0];
      *(float4*)&out[(size_t)n*C_DIM + c0] =
        make_float4(sB.x+bb.x+rq.x, sB.y+bb.y+rq.y, sB.z+bb.z+rq.z, sB.w+bb.w+rq.w);
    }
  }
}

extern "C" void kernel_launch(void* const* d_in, const int* in_sizes, int n_in,
                              void* d_out, int out_size, void* d_ws, size_t ws_size,
                              hipStream_t stream){
  const float* query     = (const float*)d_in[0];
  const float* query_pos = (const float*)d_in[1];
  const float* value     = (const float*)d_in[2];
  const float* ref       = (const float*)d_in[3];
  const unsigned char* mask = (const unsigned char*)d_in[4];
  const float* Wv   = (const float*)d_in[5];
  const float* bv   = (const float*)d_in[6];
  const float* Wo   = (const float*)d_in[7];
  const float* bo   = (const float*)d_in[8];
  const float* Wa   = (const float*)d_in[9];
  const float* ba   = (const float*)d_in[10];
  const float* Wout = (const float*)d_in[11];
  const float* bout = (const float*)d_in[12];
  float* out = (float*)d_out;

  int* flag = (int*)d_ws;
  unsigned char* v8 = (unsigned char*)((char*)d_ws + 64);  // 1,075,200 B (proven footprint)

  prep_kernel<<<VP_BLOCKS + QP_BLOCKS, 256, 0, stream>>>(
      value, Wv, bv, v8, mask, flag, query, query_pos, Wo, bo, Wa, ba, out);
  gather_kernel<<<N_Q/QPB, 256, 0, stream>>>(v8, ref, mask, flag, out);
  outproj_kernel<<<N_Q/16, 256, 0, stream>>>(Wout, bout, query, out);
}

// Round 5
// 173.785 us; speedup vs baseline: 1.0088x; 1.0088x over previous
//
#include <hip/hip_runtime.h>

#define N_Q   16384
#define C_DIM 128
#define S_CAM 6
#define M_VAL 1400   // 28*50
#define D_Z   8
#define HF    28
#define WF    50
#define QPB   8      // gather: queries per block; 32 lanes/query
#define VP_BLOCKS 1050   // (S_CAM*M_VAL)/8
#define QP_BLOCKS 1024   // N_Q/16

typedef float f32x2 __attribute__((ext_vector_type(2)));

__device__ __forceinline__ bool mask_any(const unsigned char* __restrict__ mask,
                                         int mflag, size_t mbase){
  if(mflag==0){
    int any=0;
    #pragma unroll
    for(int d=0;d<D_Z;d++) any |= mask[mbase+d];
    return any!=0;
  } else if(mflag==1){
    const int* mp = (const int*)mask;  int any=0;
    #pragma unroll
    for(int d=0;d<D_Z;d++) any |= mp[mbase+d];
    return any!=0;
  } else {
    const long long* mp = (const long long*)mask;  long long any=0;
    #pragma unroll
    for(int d=0;d<D_Z;d++) any |= mp[mbase+d];
    return any!=0;
  }
}

// fp8x16 corner accumulate as f32x2 pairs -> v_pk_fma_f32.
__device__ __forceinline__ void corner_acc(const uint4 cv, const float wgt,
                                           f32x2* __restrict__ acc2){
  const f32x2 w2 = {wgt, wgt};
  const unsigned dw[4] = {cv.x, cv.y, cv.z, cv.w};
  #pragma unroll
  for(int j=0;j<4;j++){
    acc2[j*2+0] += w2 * __builtin_amdgcn_cvt_pk_f32_fp8(dw[j], false);
    acc2[j*2+1] += w2 * __builtin_amdgcn_cvt_pk_f32_fp8(dw[j], true);
  }
}

__device__ __forceinline__ void fma4(float4& a, const float4 t,
                                     const float4 w0, const float4 w1,
                                     const float4 w2, const float4 w3){
  a.x += t.x*w0.x + t.y*w1.x + t.z*w2.x + t.w*w3.x;
  a.y += t.x*w0.y + t.y*w1.y + t.z*w2.y + t.w*w3.y;
  a.z += t.x*w0.z + t.y*w1.z + t.z*w2.z + t.w*w3.z;
  a.w += t.x*w0.w + t.y*w1.w + t.z*w2.w + t.w*w3.w;
}

__device__ __forceinline__ void shfl4_add32(float4& a){
  a.x += __shfl_xor(a.x, 32);
  a.y += __shfl_xor(a.y, 32);
  a.z += __shfl_xor(a.z, 32);
  a.w += __shfl_xor(a.w, 32);
}

// ---------------------------------------------------------------------------
// K1 = value-proj (blocks 0..1049) UNION q-proj (blocks 1050..2073).
// q-proj: offs = q@Wo+bo (out cols 0..63), attns = softmax(q@Wa+ba)
// (out cols 64..95) -- staged in the dead OUT rows, workspace stays at the
// proven ~1.08MB (flag + v8 only).
// ---------------------------------------------------------------------------
__global__ __launch_bounds__(256)
void prep_kernel(const float* __restrict__ value,
                 const float* __restrict__ Wv,
                 const float* __restrict__ bv,
                 unsigned char* __restrict__ v8,
                 const unsigned char* __restrict__ mask,
                 int* __restrict__ flag,
                 const float* __restrict__ query,
                 const float* __restrict__ query_pos,
                 const float* __restrict__ Wo, const float* __restrict__ bo,
                 const float* __restrict__ Wa, const float* __restrict__ ba,
                 float* __restrict__ out){
  __shared__ float smem[2048];               // vproj: tile+part; qproj: qtile[16][128]
  __shared__ float lbuf[16][32];             // qproj: raw logits for softmax
  __shared__ int s_cntA, s_cntB;
  const int tid = threadIdx.x;
  const int bid = blockIdx.x;

  if(bid < VP_BLOCKS){
    // ---------------- value projection -> fp8 ----------------
    float* tile = smem;                      // [8][128]
    float* part = smem + 1024;               // [8][128]
    const int c   = tid & 127;
    const int kh  = tid >> 7;
    const int r0  = bid * 8;
    if(bid==0 && tid==0){ s_cntA=0; s_cntB=0; }
    {
      const float4* src = (const float4*)(value + (size_t)r0*C_DIM);
      ((float4*)tile)[tid] = src[tid];
    }
    __syncthreads();
    float acc[8];
    {
      const float bias = kh ? 0.f : bv[c];
      #pragma unroll
      for(int r=0;r<8;r++) acc[r]=bias;
    }
    {
      const float* Wp = Wv + (size_t)kh*64*C_DIM + c;
      const int k00 = kh*64;
      for(int k0=0;k0<64;k0+=4){
        const float w0 = Wp[0];
        const float w1 = Wp[C_DIM];
        const float w2 = Wp[2*C_DIM];
        const float w3 = Wp[3*C_DIM];
        #pragma unroll
        for(int r=0;r<8;r++){
          const float4 t = *(const float4*)&tile[r*C_DIM + k00+k0];
          acc[r] += t.x*w0 + t.y*w1 + t.z*w2 + t.w*w3;
        }
        Wp += 4*C_DIM;
      }
    }
    if(kh){
      #pragma unroll
      for(int r=0;r<8;r++) part[r*C_DIM + c] = acc[r];
    }
    __syncthreads();
    if(!kh){
      #pragma unroll
      for(int r=0;r<8;r++){
        const float v = acc[r] + part[r*C_DIM + c];
        const int pk = __builtin_amdgcn_cvt_pk_fp8_f32(v, v, 0, false);
        v8[(size_t)(r0+r)*C_DIM + c] = (unsigned char)(pk & 0xff);
      }
    }
    if(bid==0){
      int a=0, b=0;
      for(int i=tid;i<1024;i+=256){
        const unsigned char v = mask[i];
        if(((i&3)!=0) && v) a=1;
        if(((i&7)==4) && v) b=1;
      }
      if(a) atomicOr(&s_cntA,1);
      if(b) atomicOr(&s_cntB,1);
      __syncthreads();
      if(tid==0) flag[0] = s_cntA ? 0 : (s_cntB ? 1 : 2);
    }
  } else {
    // ---------------- query projections + softmax ----------------
    const int qb = bid - VP_BLOCKS;
    const int n0 = qb * 16;
    float* qtile = smem;                     // [16][128]
    {
      const float4* qa = (const float4*)(query     + (size_t)n0*C_DIM);
      const float4* qp = (const float4*)(query_pos + (size_t)n0*C_DIM);
      #pragma unroll
      for(int j=0;j<2;j++){
        const int idx = tid + 256*j;
        const float4 A = qa[idx], B = qp[idx];
        *(float4*)&qtile[idx*4] = make_float4(A.x+B.x, A.y+B.y, A.z+B.z, A.w+B.w);
      }
    }
    __syncthreads();
    const int wi = tid >> 6;                 // wave: queries wi*4..wi*4+3
    const int ln = tid & 63;
    const int kh = ln >> 5;                  // k-half
    const int cg = ln & 31;                  // col-group
    float4 a0={0,0,0,0}, a1={0,0,0,0}, a2={0,0,0,0}, a3={0,0,0,0};
    if(cg < 24){
      const float* Wp; int stride; const float* bptr;
      if(cg < 16){ Wp = Wo + cg*4;      stride = 64; bptr = &bo[cg*4]; }
      else       { Wp = Wa + (cg-16)*4; stride = 32; bptr = &ba[(cg-16)*4]; }
      if(kh==0){
        const float4 bb = *(const float4*)bptr;
        a0=bb; a1=bb; a2=bb; a3=bb;
      }
      Wp += (size_t)kh*64*stride;
      const float* q0 = &qtile[(wi*4+0)*C_DIM + kh*64];
      const float* q1 = &qtile[(wi*4+1)*C_DIM + kh*64];
      const float* q2 = &qtile[(wi*4+2)*C_DIM + kh*64];
      const float* q3 = &qtile[(wi*4+3)*C_DIM + kh*64];
      #pragma unroll 4
      for(int k0=0;k0<64;k0+=4){
        const float4 w0 = *(const float4*)&Wp[0];
        const float4 w1 = *(const float4*)&Wp[stride];
        const float4 w2 = *(const float4*)&Wp[2*stride];
        const float4 w3 = *(const float4*)&Wp[3*stride];
        fma4(a0, *(const float4*)&q0[k0], w0,w1,w2,w3);
        fma4(a1, *(const float4*)&q1[k0], w0,w1,w2,w3);
        fma4(a2, *(const float4*)&q2[k0], w0,w1,w2,w3);
        fma4(a3, *(const float4*)&q3[k0], w0,w1,w2,w3);
        Wp += 4*stride;
      }
    }
    shfl4_add32(a0); shfl4_add32(a1); shfl4_add32(a2); shfl4_add32(a3);
    if(cg < 16){
      const int c0 = cg*4;
      const int r  = wi*4 + kh*2;            // kh=0 -> rows 0,1; kh=1 -> rows 2,3
      const float4 sA = kh ? a2 : a0;
      const float4 sB = kh ? a3 : a1;
      *(float4*)&out[(size_t)(n0+r  )*C_DIM + c0] = sA;
      *(float4*)&out[(size_t)(n0+r+1)*C_DIM + c0] = sB;
    } else if(cg < 24){
      const int c0 = (cg-16)*4;
      const int r  = wi*4 + kh*2;
      *(float4*)&lbuf[r  ][c0] = kh ? a2 : a0;
      *(float4*)&lbuf[r+1][c0] = kh ? a3 : a1;
    }
    __syncthreads();
    if(tid < 64){                            // softmax over P=8: (q, h)
      const int q = tid >> 2, h = tid & 3;
      const float* L = &lbuf[q][h*8];
      float mx = L[0];
      #pragma unroll
      for(int p=1;p<8;p++) mx = fmaxf(mx, L[p]);
      float e[8], ssum = 0.f;
      #pragma unroll
      for(int p=0;p<8;p++){ e[p] = __expf(L[p]-mx); ssum += e[p]; }
      const float inv = 1.f/ssum;
      float* dst = &out[(size_t)(n0+q)*C_DIM + 64 + h*8];
      *(float4*)dst     = make_float4(e[0]*inv, e[1]*inv, e[2]*inv, e[3]*inv);
      *(float4*)(dst+4) = make_float4(e[4]*inv, e[5]*inv, e[6]*inv, e[7]*inv);
    }
  }
}

// ---------------------------------------------------------------------------
// K2: gather + out-proj fused (R5). R4 established the gather sits ~20% above
// the scatter-TA addr-rate floor (25.1M lane-addrs / 1 per cy/CU = 41us) with
// VALU only 37% busy. A TA-bound kernel absorbs COALESCED GEMV work nearly
// free: outproj adds ~64 coalesced weight loads (~500 TA cy, +5%) and ~2.6K
// VALU cy/wave that fill the stall gaps. Slots stay in LDS (qs) -- no HBM
// round-trip, no 3rd dispatch. The GEMV's qs reads are wave-broadcast
// (same addr across lanes = conflict-free). Post-merge slot write (lanes l<8)
// and the GEMV reads are same-wave DS ops -> in-order, no barrier needed.
// ---------------------------------------------------------------------------
__global__ __launch_bounds__(256)
void gather_kernel(const unsigned char* __restrict__ v8,
                   const float* __restrict__ ref,
                   const unsigned char* __restrict__ mask,
                   const int* __restrict__ flag,
                   const float* __restrict__ query,
                   const float* __restrict__ Wout,
                   const float* __restrict__ bout,
                   float* __restrict__ out){
  __shared__ float  qs[QPB][C_DIM+4];        // slot rows (132 floats: 16B-aligned rows)
  __shared__ float  offs[QPB][68];           // 68 mod 32 = 4
  __shared__ float  attns[QPB][36];
  __shared__ float2 refs[QPB][S_CAM*D_Z+1];  // 49 f2 rows
  __shared__ int    activ[QPB][S_CAM];
  __shared__ float  cinv[QPB];

  const int tid = threadIdx.x;
  const int n0  = blockIdx.x * QPB;
  const int mflag = flag[0];
  const int qi = tid >> 5;                   // query in block
  const int l  = tid & 31;                   // lane within query group

  // ---- staging: offs/attns from out rows (cols 0..95), refs, activ, cinv ----
  if(tid < 192){                             // 8q x 24 f4 = offs(16) + attns(8)
    const int q = tid/24, j = tid%24;
    const float4 v = *(const float4*)&out[(size_t)(n0+q)*C_DIM + j*4];
    if(j<16) *(float4*)&offs[q][j*4] = v;
    else     *(float4*)&attns[q][(j-16)*4] = v;
  }
  {
    const int q = tid/48, r = tid%48;        // r = s*8+p
    refs[q][r] = ((const float2*)ref)[((size_t)(r>>3)*N_Q + (n0+q))*D_Z + (r&7)];
    if(tid < 128){
      const int e1 = tid + 256;
      const int q1 = e1/48, r1 = e1%48;
      refs[q1][r1] = ((const float2*)ref)[((size_t)(r1>>3)*N_Q + (n0+q1))*D_Z + (r1&7)];
    }
  }
  if(tid < QPB*S_CAM){
    const int q2 = tid / S_CAM, s = tid % S_CAM;
    activ[q2][s] = mask_any(mask, mflag, ((size_t)s*N_Q + (n0+q2))*D_Z) ? 1 : 0;
  } else if(tid < QPB*S_CAM + QPB){
    const int q2 = tid - QPB*S_CAM;
    int c = 0;
    #pragma unroll
    for(int s=0;s<S_CAM;s++)
      c += mask_any(mask, mflag, ((size_t)s*N_Q + (n0+q2))*D_Z) ? 1 : 0;
    cinv[q2] = 1.f / fmaxf((float)c, 1.f);
  }
  __syncthreads();                           // staging reads done before out overwrite

  // ---- gather: 3 cams x 4 points per lane ----
  const int pg  = l >> 4;                    // points pg*4 .. pg*4+3
  const int sg  = (l >> 3) & 1;              // cams sg*3 .. sg*3+2
  const int ll  = l & 7;                     // 16-ch group
  const int gch = ll*16;
  const int gh  = ll >> 1;                   // head (32 ch/head)
  f32x2 acc2[8];
  #pragma unroll
  for(int i=0;i<8;i++) acc2[i] = (f32x2){0.f, 0.f};

  for(int s=sg*3; s<sg*3+3; s++){
    if(!activ[qi][s]) continue;
    const unsigned char* vb = v8 + (size_t)s*M_VAL*C_DIM + gch;
    #pragma unroll 2
    for(int pp=0;pp<4;pp++){                 // point p <-> z-anchor d=p (P//D==1)
      const int p = pg*4 + pp;
      const float2 r2 = refs[qi][s*8+p];
      const float ox = offs[qi][gh*16+p*2+0];
      const float oy = offs[qi][gh*16+p*2+1];
      const float x = fmaf(r2.x, (float)WF, ox - 0.5f);
      const float y = fmaf(r2.y, (float)HF, oy - 0.5f);
      const float x0f = floorf(x), y0f = floorf(y);
      const float fx = x - x0f,    fy = y - y0f;
      const int x0 = (int)x0f, y0 = (int)y0f;
      const int x1 = x0+1,     y1 = y0+1;
      const float at = attns[qi][gh*8+p];
      const float wx0 = (x0>=0 && x0<WF) ? (1.f-fx) : 0.f;
      const float wx1 = (x1>=0 && x1<WF) ? fx       : 0.f;
      const float wy0 = ((y0>=0 && y0<HF) ? (1.f-fy) : 0.f) * at;
      const float wy1 = ((y1>=0 && y1<HF) ? fy       : 0.f) * at;
      const int x0c = min(max(x0,0), WF-1), x1c = min(max(x1,0), WF-1);
      const int y0c = min(max(y0,0), HF-1), y1c = min(max(y1,0), HF-1);
      const float w00 = wx0*wy0, w01 = wx1*wy0, w10 = wx0*wy1, w11 = wx1*wy1;
      const uint4 c00 = *(const uint4*)(vb + (size_t)(y0c*WF+x0c)*C_DIM);
      const uint4 c01 = *(const uint4*)(vb + (size_t)(y0c*WF+x1c)*C_DIM);
      const uint4 c10 = *(const uint4*)(vb + (size_t)(y1c*WF+x0c)*C_DIM);
      const uint4 c11 = *(const uint4*)(vb + (size_t)(y1c*WF+x1c)*C_DIM);
      corner_acc(c00, w00, acc2);
      corner_acc(c01, w01, acc2);
      corner_acc(c10, w10, acc2);
      corner_acc(c11, w11, acc2);
    }
  }

  // ---- merge 4 (pg,sg) partials; slot rows -> LDS (same-wave producers) ----
  float* accf = (float*)acc2;
  #pragma unroll
  for(int i=0;i<16;i++) accf[i] += __shfl_xor(accf[i], 16);  // merge pt halves
  #pragma unroll
  for(int i=0;i<16;i++) accf[i] += __shfl_xor(accf[i], 8);   // merge cam halves
  if(l < 8){
    const float inv = cinv[qi];
    #pragma unroll
    for(int i=0;i<4;i++)
      *(float4*)&qs[qi][gch+i*4] = make_float4(accf[i*4+0]*inv, accf[i*4+1]*inv,
                                               accf[i*4+2]*inv, accf[i*4+3]*inv);
  }
  // qs rows 2wi/2wi+1 written and read only by this wave; DS ops of one wave
  // complete in program order -> no block barrier needed.

  // ---- out-proj + bias + residual, k-split across the wave's halves ----
  {
    const int wi2 = tid >> 6;                // wave -> queries 2wi2, 2wi2+1
    const int ln  = tid & 63;
    const int kh  = ln >> 5;                 // k-half
    const int cg  = ln & 31;                 // 4-col group
    const int qA = 2*wi2, qB = qA+1;
    const int c0 = cg*4;
    float4 aA={0,0,0,0}, aB={0,0,0,0};
    if(kh==0){                               // bias+residual added once
      const float4 bb = *(const float4*)&bout[c0];
      const float4 rA = *(const float4*)&query[(size_t)(n0+qA)*C_DIM + c0];
      const float4 rB = *(const float4*)&query[(size_t)(n0+qB)*C_DIM + c0];
      aA = make_float4(bb.x+rA.x, bb.y+rA.y, bb.z+rA.z, bb.w+rA.w);
      aB = make_float4(bb.x+rB.x, bb.y+rB.y, bb.z+rB.z, bb.w+rB.w);
    }
    const float* Wp = Wout + (size_t)kh*64*C_DIM + c0;
    const float* sA = &qs[qA][kh*64];        // broadcast reads (same addr/lane)
    const float* sB = &qs[qB][kh*64];
    #pragma unroll 4
    for(int k0=0;k0<64;k0+=4){
      const float4 w0 = *(const float4*)&Wp[0];
      const float4 w1 = *(const float4*)&Wp[C_DIM];
      const float4 w2 = *(const float4*)&Wp[2*C_DIM];
      const float4 w3 = *(const float4*)&Wp[3*C_DIM];
      fma4(aA, *(const float4*)&sA[k0], w0,w1,w2,w3);
      fma4(aB, *(const float4*)&sB[k0], w0,w1,w2,w3);
      Wp += 4*C_DIM;
    }
    shfl4_add32(aA); shfl4_add32(aB);
    const float4 rs = kh ? aB : aA;          // kh=0 stores qA, kh=1 stores qB
    *(float4*)&out[(size_t)(n0+qA+kh)*C_DIM + c0] = rs;
  }
}

extern "C" void kernel_launch(void* const* d_in, const int* in_sizes, int n_in,
                              void* d_out, int out_size, void* d_ws, size_t ws_size,
                              hipStream_t stream){
  const float* query     = (const float*)d_in[0];
  const float* query_pos = (const float*)d_in[1];
  const float* value     = (const float*)d_in[2];
  const float* ref       = (const float*)d_in[3];
  const unsigned char* mask = (const unsigned char*)d_in[4];
  const float* Wv   = (const float*)d_in[5];
  const float* bv   = (const float*)d_in[6];
  const float* Wo   = (const float*)d_in[7];
  const float* bo   = (const float*)d_in[8];
  const float* Wa   = (const float*)d_in[9];
  const float* ba   = (const float*)d_in[10];
  const float* Wout = (const float*)d_in[11];
  const float* bout = (const float*)d_in[12];
  float* out = (float*)d_out;

  int* flag = (int*)d_ws;
  unsigned char* v8 = (unsigned char*)((char*)d_ws + 64);  // 1,075,200 B (proven footprint)

  prep_kernel<<<VP_BLOCKS + QP_BLOCKS, 256, 0, stream>>>(
      value, Wv, bv, v8, mask, flag, query, query_pos, Wo, bo, Wa, ba, out);
  gather_kernel<<<N_Q/QPB, 256, 0, stream>>>(v8, ref, mask, flag,
                                             query, Wout, bout, out);
}